// Round 11
// baseline (204.621 us; speedup 1.0000x reference)
//
#include <hip/hip_runtime.h>

// NCC loss: five 9x9x9 box sums (I, J, I^2, J^2, I*J), stride 1, pad 4,
// count_include_pad (divisor 729), ncc = cov^2/(varI*varJ+eps), out = -mean.
// Shapes fixed: [2,1,192,192,192] fp32.
//
// R18 == R17 resubmitted verbatim (R17 bench never ran: container failed
// twice, no counters).
//
// R17 = R16 + TREE-SHAPED YSTEP (single variable).
// R16 verdict: rcp-EMIT isolated = neutral (108us == R7) -> EMIT VALU count
// not on critical path; kept (pressure-reducing, absmax 0).
// Session ledger: else-zero LOAD kills the compiler's prefetch renaming
// (+36us, R15); any unroll/state widening trips the 128-VGPR allocator pin
// and spills rings (R8-R14). Remaining untested mechanism inside R7's
// structure: the 9-deep sequential y-sum add chain (~36cy/component serial,
// only 2 waves/SIMD to hide it). Tree over rows 1..8:
//   a18 = ((r1+r2)+(r3+r4)) + ((r5+r6)+(r7+r8))   depth 3
//   s4  = t0 + a18   (rows 0..8)                  depth 4 (was 9)
//   sB4 = a18 + t9   (rows 1..9) -- subtract eliminated (9 adds, was 10)
// Peak live float4s ~5 (NOT R9's all-loads-first 50 -> no spill trigger).
// Everything else byte-identical to R16: unconditional-zero LOAD (prefetch
// renaming), dynamic buffer parity, 4x9+tail loop, lgkmcnt-only barrier,
// xs1 stride 20, named-scalar z-rings, 16x32 tile, 2 y-outputs/thread,
// XCD swizzle, launch_bounds(256,2).

#define S    192
#define SS   (S * S)
#define TX   16
#define YT   32                  // y-tile; thread (tx,tyt) owns y=2*tyt,2*tyt+1
#define NTHR 256
#define KZ   32
#define RAD  4
#define WIN  9
#define NSL  (KZ + 2 * RAD)      // 40
#define HXR  (YT + 2 * RAD)      // 40 halo rows
#define XSW  17                  // xs4 padded row stride (float4 units)
#define XSW1 20                  // xs1 padded row stride (floats): banks 8t+tx
#define NVOX (2.0 * S * S * S)

// LDS-only barrier: waves' DS ops complete (lgkmcnt) + rendezvous. No vmcnt
// drain -> global prefetch survives the barrier.
#define LDS_BARRIER() __asm__ __volatile__("s_waitcnt lgkmcnt(0)\n\ts_barrier" ::: "memory")

__global__ void ncc_init(double* ws) { ws[0] = 0.0; }

__global__ void ncc_final(const double* __restrict__ ws, float* __restrict__ out) {
    out[0] = (float)(-ws[0] / NVOX);
}

__device__ __forceinline__ float4 f4add(float4 a, float4 b) {
    return make_float4(a.x + b.x, a.y + b.y, a.z + b.z, a.w + b.w);
}
__device__ __forceinline__ float4 f4sub(float4 a, float4 b) {
    return make_float4(a.x - b.x, a.y - b.y, a.z - b.z, a.w - b.w);
}

__global__ __launch_bounds__(NTHR, 2) void ncc_main(const float* __restrict__ I,
                                                    const float* __restrict__ J,
                                                    double* __restrict__ ws) {
    // LDS ~28 KB: xs4 2*40*17*16 + xs1 2*40*20*4 + red
    __shared__ float4 xs4[2][HXR][XSW];    // (sI, sJ, sI2, sJ2)
    __shared__ float  xs1[2][HXR][XSW1];   // sIJ
    __shared__ float  red[4];

    const int tid = threadIdx.x;          // 0..255 (flat)
    const int tx  = tid & 15;
    const int tyt = tid >> 4;             // 0..15 -> outputs y=2*tyt, 2*tyt+1

    // XCD swizzle over 864 blocks: id&7 = XCD owns a 3x3 xy-patch, bijective.
    const int id  = blockIdx.x;           // 0..863
    const int xcd = id & 7;
    const int lo  = id >> 3;              // 0..107
    const int t   = lo % 9;
    const int bzq = lo / 9;               // 0..11
    const int bx  = (xcd & 3) * 3 + t % 3;     // 0..11
    const int by  = (xcd >> 2) * 3 + t / 3;    // 0..5
    const int b   = (bzq >= 6) ? 1 : 0;
    const int zc  = bzq - 6 * b;
    const int x0 = bx * TX, y0 = by * YT, z0 = zc * KZ;

    const float* Ib = I + (size_t)b * S * SS;
    const float* Jb = J + (size_t)b * S * SS;

    // x-tasks: 160 threads, task (row xr 0..39, quad xq 0..3) -> 4 x-outputs
    // from 12 input cols (4-aligned chunks, all-valid or all-invalid).
    const bool xtask = (tid < 4 * HXR);
    const int  xr  = tid >> 2;            // 0..39
    const int  xq  = tid & 3;
    const int  gy  = y0 - RAD + xr;
    const bool gyv = xtask && ((unsigned)gy < (unsigned)S);
    const int  c0  = x0 + 4 * xq - RAD;
    const bool cv0 = gyv && ((unsigned)(c0    ) < (unsigned)S);
    const bool cv1 = gyv && ((unsigned)(c0 + 4) < (unsigned)S);
    const bool cv2 = gyv && ((unsigned)(c0 + 8) < (unsigned)S);
    const ptrdiff_t rowoff = gyv ? ((ptrdiff_t)gy * S + c0) : 0;

    float4 li0, li1, li2, lj0, lj1, lj2;

    auto LOAD = [&](int p) {
        // Unconditional zeroing: full redefinition -> fresh SSA values each
        // slice -> compiler hoists these loads early into renamed physical
        // regs (prefetch). DO NOT convert to else-branch zeroing (R15: +36us).
        li0 = li1 = li2 = lj0 = lj1 = lj2 = make_float4(0.f, 0.f, 0.f, 0.f);
        if (p < NSL) {
            const int zi = z0 - RAD + p;
            if ((unsigned)zi < (unsigned)S) {
                const float* rI = Ib + (size_t)zi * SS + rowoff;
                const float* rJ = Jb + (size_t)zi * SS + rowoff;
                if (cv0) { li0 = *(const float4*)(rI);     lj0 = *(const float4*)(rJ); }
                if (cv1) { li1 = *(const float4*)(rI + 4); lj1 = *(const float4*)(rJ + 4); }
                if (cv2) { li2 = *(const float4*)(rI + 8); lj2 = *(const float4*)(rJ + 8); }
            }
        }
    };

    auto XPHASE = [&](int p) {
        if (xtask) {
            const float iv[12] = { li0.x, li0.y, li0.z, li0.w,
                                   li1.x, li1.y, li1.z, li1.w,
                                   li2.x, li2.y, li2.z, li2.w };
            const float jv[12] = { lj0.x, lj0.y, lj0.z, lj0.w,
                                   lj1.x, lj1.y, lj1.z, lj1.w,
                                   lj2.x, lj2.y, lj2.z, lj2.w };
            float a = 0.f, bb = 0.f, c = 0.f, d = 0.f, e = 0.f;
            #pragma unroll
            for (int m = 0; m < WIN; ++m) {
                a += iv[m];
                bb += jv[m];
                c = fmaf(iv[m], iv[m], c);
                d = fmaf(jv[m], jv[m], d);
                e = fmaf(iv[m], jv[m], e);
            }
            const int cb = p & 1;
            #pragma unroll
            for (int k = 0; k < 4; ++k) {
                if (k > 0) {
                    a += iv[8 + k] - iv[k - 1];
                    bb += jv[8 + k] - jv[k - 1];
                    c += fmaf(iv[8 + k], iv[8 + k], -iv[k - 1] * iv[k - 1]);
                    d += fmaf(jv[8 + k], jv[8 + k], -jv[k - 1] * jv[k - 1]);
                    e += fmaf(iv[8 + k], jv[8 + k], -iv[k - 1] * jv[k - 1]);
                }
                xs4[cb][xr][4 * xq + k] = make_float4(a, bb, c, d);
                xs1[cb][xr][4 * xq + k] = e;
            }
        }
    };

    // z-rings as NAMED scalars (no arrays -> no scratch demotion possible).
    const float4 F40 = make_float4(0.f, 0.f, 0.f, 0.f);
    float4 a4_0 = F40, a4_1 = F40, a4_2 = F40, a4_3 = F40, a4_4 = F40,
           a4_5 = F40, a4_6 = F40, a4_7 = F40, a4_8 = F40;
    float  a1_0 = 0.f, a1_1 = 0.f, a1_2 = 0.f, a1_3 = 0.f, a1_4 = 0.f,
           a1_5 = 0.f, a1_6 = 0.f, a1_7 = 0.f, a1_8 = 0.f;
    float4 b4_0 = F40, b4_1 = F40, b4_2 = F40, b4_3 = F40, b4_4 = F40,
           b4_5 = F40, b4_6 = F40, b4_7 = F40, b4_8 = F40;
    float  b1_0 = 0.f, b1_1 = 0.f, b1_2 = 0.f, b1_3 = 0.f, b1_4 = 0.f,
           b1_5 = 0.f, b1_6 = 0.f, b1_7 = 0.f, b1_8 = 0.f;
    float4 runA4 = F40, runB4 = F40;
    float  runA1 = 0.f, runB1 = 0.f;
    float  acc = 0.f;
    const int yA = 2 * tyt;               // taps yA..yA+9 cover both outputs

    // One-instruction reciprocal (v_rcp_f32, ~1 ulp): final |err| ~1e-10 abs.
#define EMIT(R4, R1) do {                                                   \
        const float inv_ = 1.0f / 729.0f;                                   \
        const float mI_ = (R4).x * inv_, mJ_ = (R4).y * inv_;               \
        const float vI_ = (R4).z * inv_ - mI_ * mI_;                        \
        const float vJ_ = (R4).w * inv_ - mJ_ * mJ_;                        \
        const float cIJ_ = (R1) * inv_ - mI_ * mJ_;                         \
        acc = fmaf(cIJ_ * cIJ_,                                             \
                   __builtin_amdgcn_rcpf(vI_ * vJ_ + 1e-5f), acc);          \
    } while (0)

    // Tree y-sum: a18 = rows 1..8 pairwise (depth 3); s4 = t0+a18 (rows
    // 0..8); sB4 = a18+t9 (rows 1..9, no subtract). Incremental pair loads
    // keep peak live ~5 float4s (pressure-safe, unlike R9's 50).
#define YSTEP(P, K) do {                                                    \
        const int pb_ = (P) & 1;                                            \
        const float4 t0_4 = xs4[pb_][yA + 0][tx];                           \
        const float  t0_1 = xs1[pb_][yA + 0][tx];                           \
        float4 u1_4 = xs4[pb_][yA + 1][tx], u2_4 = xs4[pb_][yA + 2][tx];    \
        float  u1_1 = xs1[pb_][yA + 1][tx], u2_1 = xs1[pb_][yA + 2][tx];    \
        float4 p12_4 = f4add(u1_4, u2_4);  float p12_1 = u1_1 + u2_1;       \
        float4 u3_4 = xs4[pb_][yA + 3][tx], u4_4 = xs4[pb_][yA + 4][tx];    \
        float  u3_1 = xs1[pb_][yA + 3][tx], u4_1 = xs1[pb_][yA + 4][tx];    \
        float4 p34_4 = f4add(u3_4, u4_4);  float p34_1 = u3_1 + u4_1;       \
        float4 p14_4 = f4add(p12_4, p34_4); float p14_1 = p12_1 + p34_1;    \
        float4 u5_4 = xs4[pb_][yA + 5][tx], u6_4 = xs4[pb_][yA + 6][tx];    \
        float  u5_1 = xs1[pb_][yA + 5][tx], u6_1 = xs1[pb_][yA + 6][tx];    \
        float4 p56_4 = f4add(u5_4, u6_4);  float p56_1 = u5_1 + u6_1;       \
        float4 u7_4 = xs4[pb_][yA + 7][tx], u8_4 = xs4[pb_][yA + 8][tx];    \
        float  u7_1 = xs1[pb_][yA + 7][tx], u8_1 = xs1[pb_][yA + 8][tx];    \
        float4 p78_4 = f4add(u7_4, u8_4);  float p78_1 = u7_1 + u8_1;       \
        float4 p58_4 = f4add(p56_4, p78_4); float p58_1 = p56_1 + p78_1;    \
        const float4 a18_4 = f4add(p14_4, p58_4);                           \
        const float  a18_1 = p14_1 + p58_1;                                 \
        const float4 t9_4 = xs4[pb_][yA + WIN][tx];                         \
        const float  t9_1 = xs1[pb_][yA + WIN][tx];                         \
        const float4 s4  = f4add(t0_4, a18_4);                              \
        const float  s1  = t0_1 + a18_1;                                    \
        const float4 sB4 = f4add(a18_4, t9_4);                              \
        const float  sB1 = a18_1 + t9_1;                                    \
        runA4 = f4add(runA4, f4sub(s4, a4_##K));   a4_##K = s4;             \
        runA1 += s1 - a1_##K;                      a1_##K = s1;             \
        runB4 = f4add(runB4, f4sub(sB4, b4_##K));  b4_##K = sB4;            \
        runB1 += sB1 - b1_##K;                     b1_##K = sB1;            \
        if ((P) >= 2 * RAD) { EMIT(runA4, runA1); EMIT(runB4, runB1); }     \
    } while (0)

#define BODY(K) { YSTEP(idx - 1, K); XPHASE(idx); LOAD(idx + 1);            \
                  LDS_BARRIER(); ++idx; }

    // Pipeline: [y(idx-1) | x(idx) | load(idx+1) | lds-barrier] per slice.
    LOAD(0);
    XPHASE(0);
    LOAD(1);
    LDS_BARRIER();

    int idx = 1;
    #pragma unroll 1
    for (int g = 0; g < 4; ++g) {        // y-index p=idx-1 = 0..35, K=p%9
        BODY(0) BODY(1) BODY(2) BODY(3) BODY(4)
        BODY(5) BODY(6) BODY(7) BODY(8)
    }
    BODY(0) BODY(1) BODY(2)              // p = 36,37,38 -> K 0,1,2
    YSTEP(NSL - 1, 3);                   // p = 39 -> 39%9 = 3
#undef BODY
#undef YSTEP
#undef EMIT

    // Block reduction: wave shuffle -> LDS -> one double atomic.
    // (Full __syncthreads here is fine: once per block, nothing to prefetch.)
    float v = acc;
    #pragma unroll
    for (int off = 32; off >= 1; off >>= 1)
        v += __shfl_down(v, off, 64);
    const int lane = tid & 63;
    const int wid  = tid >> 6;
    if (lane == 0) red[wid] = v;
    __syncthreads();
    if (tid == 0) {
        atomicAdd(ws, (double)(red[0] + red[1] + red[2] + red[3]));
    }
}

extern "C" void kernel_launch(void* const* d_in, const int* in_sizes, int n_in,
                              void* d_out, int out_size, void* d_ws, size_t ws_size,
                              hipStream_t stream) {
    const float* I = (const float*)d_in[0];   // y_pred
    const float* J = (const float*)d_in[1];   // y_true
    double* ws = (double*)d_ws;
    float* out = (float*)d_out;

    hipLaunchKernelGGL(ncc_init, dim3(1), dim3(1), 0, stream, ws);

    hipLaunchKernelGGL(ncc_main, dim3(12 * 6 * 12), dim3(NTHR), 0, stream,
                       I, J, ws);

    hipLaunchKernelGGL(ncc_final, dim3(1), dim3(1), 0, stream, ws, out);
}